// Round 1
// baseline (211.738 us; speedup 1.0000x reference)
//
#include <hip/hip_runtime.h>

#define B_ 4
#define N_ 1024
#define H_ 256
#define D_ 32

// ws layout (floats)
#define OFF_KVB 0                       // [b][n][64]  k(0..31) | v(32..63)
#define OFF_DD  (B_*N_*64)              // [b][n][32]
#define OFF_KH  (OFF_DD + B_*N_*32)     // [b][h][n]
#define OFF_VH  (OFF_KH + B_*H_*N_)     // [b][h][n]
#define OFF_DH  (OFF_VH + B_*H_*N_)     // [b][h][n]

__device__ __forceinline__ float rcp_fast(float x) {
#if __has_builtin(__builtin_amdgcn_rcpf)
  return __builtin_amdgcn_rcpf(x);
#else
  return 1.0f / x;
#endif
}
__device__ __forceinline__ float sigm(float x) { return rcp_fast(1.0f + __expf(-x)); }

// ---------------- Kernel A: projections ----------------
// token (4096 x 256) @ {W_kv(256x64), W_kvh(256x512), W_decay(256x32), W_decayh(256x256)}
// grid = (64 row tiles, 14 col jobs), block = 256 (16x16), 64x64 tile, 4x4/thread.
__global__ __launch_bounds__(256) void proj_gemm(
    const float* __restrict__ token,
    const float* __restrict__ Wkv,
    const float* __restrict__ Wkvh,
    const float* __restrict__ Wdec,
    const float* __restrict__ Wdech,
    float* __restrict__ ws)
{
  const int job = blockIdx.y;
  const float* Wp; int ldw, c0, ncols, mode;
  if (job == 0)      { Wp = Wkv;   ldw = 64;  c0 = 0;           ncols = 64;  mode = 0; }
  else if (job <= 8) { Wp = Wkvh;  ldw = 512; c0 = (job-1)*64;  ncols = 512; mode = 1; }
  else if (job == 9) { Wp = Wdec;  ldw = 32;  c0 = 0;           ncols = 32;  mode = 2; }
  else               { Wp = Wdech; ldw = 256; c0 = (job-10)*64; ncols = 256; mode = 3; }

  __shared__ float As[16][68];   // [k][row], pad 68 keeps 16B align + low conflicts
  __shared__ float Bs[16][68];   // [k][col]

  const int tid = threadIdx.x;
  const int tx = tid & 15, ty = tid >> 4;
  const int r0 = blockIdx.x * 64;

  const int arow = tid >> 2, akk = (tid & 3) * 4;
  const int bkk = tid >> 4, bc4 = (tid & 15) * 4;
  const bool bvalid = (c0 + bc4 + 3) < ncols;   // only false for decay job cols>=32

  float acc[4][4] = {{0.f,0.f,0.f,0.f},{0.f,0.f,0.f,0.f},{0.f,0.f,0.f,0.f},{0.f,0.f,0.f,0.f}};

  for (int k0 = 0; k0 < H_; k0 += 16) {
    const float4 av = *reinterpret_cast<const float4*>(&token[(r0 + arow) * H_ + k0 + akk]);
    float4 bv = make_float4(0.f, 0.f, 0.f, 0.f);
    if (bvalid) bv = *reinterpret_cast<const float4*>(&Wp[(k0 + bkk) * ldw + c0 + bc4]);
    __syncthreads();             // protect previous iteration's LDS reads
    As[akk+0][arow] = av.x; As[akk+1][arow] = av.y;
    As[akk+2][arow] = av.z; As[akk+3][arow] = av.w;
    *reinterpret_cast<float4*>(&Bs[bkk][bc4]) = bv;
    __syncthreads();
#pragma unroll
    for (int kk = 0; kk < 16; ++kk) {
      const float4 a4 = *reinterpret_cast<const float4*>(&As[kk][ty*4]);
      const float4 b4 = *reinterpret_cast<const float4*>(&Bs[kk][tx*4]);
      const float a[4]  = {a4.x, a4.y, a4.z, a4.w};
      const float bb[4] = {b4.x, b4.y, b4.z, b4.w};
#pragma unroll
      for (int i2 = 0; i2 < 4; ++i2)
#pragma unroll
        for (int j2 = 0; j2 < 4; ++j2)
          acc[i2][j2] = fmaf(a[i2], bb[j2], acc[i2][j2]);
    }
  }

  const int b  = r0 >> 10;              // 64 | 1024 so b is block-uniform
  const int n0 = (r0 & (N_-1)) + ty*4;

  if (mode == 0) {
#pragma unroll
    for (int i2 = 0; i2 < 4; ++i2) {
      float4 st = make_float4(acc[i2][0], acc[i2][1], acc[i2][2], acc[i2][3]);
      *reinterpret_cast<float4*>(&ws[OFF_KVB + (r0 + ty*4 + i2)*64 + tx*4]) = st;
    }
  } else if (mode == 2) {
    if (tx*4 < 32) {
#pragma unroll
      for (int i2 = 0; i2 < 4; ++i2) {
        float4 st = make_float4(acc[i2][0], acc[i2][1], acc[i2][2], acc[i2][3]);
        *reinterpret_cast<float4*>(&ws[OFF_DD + (r0 + ty*4 + i2)*32 + tx*4]) = st;
      }
    }
  } else {  // transposed stores: [b][col][n]
#pragma unroll
    for (int j2 = 0; j2 < 4; ++j2) {
      const int ch = c0 + tx*4 + j2;
      float* dst;
      if (mode == 1) {
        dst = (ch < H_) ? &ws[OFF_KH + ((b*H_ + ch) << 10) + n0]
                        : &ws[OFF_VH + ((b*H_ + (ch - H_)) << 10) + n0];
      } else {
        dst = &ws[OFF_DH + ((b*H_ + ch) << 10) + n0];
      }
      float4 st = make_float4(acc[0][j2], acc[1][j2], acc[2][j2], acc[3][j2]);
      *reinterpret_cast<float4*>(dst) = st;
    }
  }
}

// ---------------- Kernel B: decay scan + 32x32 outer product ----------------
// One block per (b,h). 4 waves = 4 chunks of 256 along n.
// weight[i,d] = prod_{u=1..i} sigmoid(decay[N-u,d])  (== exp(cumsum(log_sigmoid)))
__global__ __launch_bounds__(256) void scan_outer(const float* __restrict__ ws,
                                                  float* __restrict__ out)
{
  const int bh = blockIdx.x;
  const int b = bh >> 8, h = bh & (H_-1);
  const int tid = threadIdx.x;
  const int w = tid >> 6;          // wave/chunk 0..3
  const int lane = tid & 63;
  const int d = lane & 31;

  const float* kvb = ws + OFF_KVB + b * (N_*64);
  const float* dd  = ws + OFF_DD  + b * (N_*32);
  const float* kh  = ws + OFF_KH + ((b*H_ + h) << 10);
  const float* vh  = ws + OFF_VH + ((b*H_ + h) << 10);
  const float* dh  = ws + OFF_DH + ((b*H_ + h) << 10);

  __shared__ float q_lds[96];          // chunk-total products Q_w[d], w=0..2
  __shared__ float acc_lds[4][1024];

  // Phase 1: Q_w[d] = prod over rows [N-(w+1)*256, N-w*256) of sigmoid(decay[row,d])
  if (w < 3) {
    const int m0 = N_ - (w+1)*256;
    float p = 1.0f;
    for (int s = 0; s < 128; ++s) {
      const int row = m0 + 2*s + (lane >> 5);
      p *= sigm(dd[row*32 + d] * dh[row]);
    }
    p *= __shfl_xor(p, 32, 64);        // combine the two half-wave partials
    if (lane < 32) q_lds[w*32 + d] = p;
  }
  __syncthreads();

  // Phase 2: local scan with carry P_w = prod_{w'<w} Q_w'
  float run = 1.0f;
#pragma unroll
  for (int w2 = 0; w2 < 3; ++w2)
    if (w2 < w) run *= q_lds[w2*32 + d];

  float acc[4][4] = {{0.f,0.f,0.f,0.f},{0.f,0.f,0.f,0.f},{0.f,0.f,0.f,0.f},{0.f,0.f,0.f,0.f}};
  const int d4 = (lane & 7) * 4;       // 8x8 lane grid of 4x4 tiles
  const int e4 = (lane >> 3) * 4;
  const int i0 = w * 256;

  for (int t = 0; t < 256; ++t) {
    const int i = i0 + t;
    const float val = kvb[i*64 + lane];               // lanes<32: k-proj, >=32: v-proj
    const float sc  = (lane < 32) ? kh[i] : vh[i];    // uniform s_loads + select
    const int mr = (i == 0) ? 1 : (N_ - i);           // clamp keeps load in-bounds; factor unused at i==0
    const float dx = dd[mr*32 + d] * dh[mr];
    const float x  = val * sc;
    const float sv = x * sigm(x);                     // silu
    const float fs = sigm(dx);
    if (i > 0) run *= fs;                             // wave-uniform branch
    const float myv = (lane < 32) ? sv * run : sv;

    float a4v[4], b4v[4];
#pragma unroll
    for (int p2 = 0; p2 < 4; ++p2) a4v[p2] = __shfl(myv, d4 + p2, 64);
#pragma unroll
    for (int q2 = 0; q2 < 4; ++q2) b4v[q2] = __shfl(myv, 32 + e4 + q2, 64);
#pragma unroll
    for (int p2 = 0; p2 < 4; ++p2)
#pragma unroll
      for (int q2 = 0; q2 < 4; ++q2)
        acc[p2][q2] = fmaf(a4v[p2], b4v[q2], acc[p2][q2]);
  }

  // Combine the 4 chunk partials and store
#pragma unroll
  for (int p2 = 0; p2 < 4; ++p2)
#pragma unroll
    for (int q2 = 0; q2 < 4; ++q2)
      acc_lds[w][(d4+p2)*32 + (e4+q2)] = acc[p2][q2];
  __syncthreads();

  {
    const int el = tid * 4;   // 256 threads x 4 contiguous elements = 1024
    const float4 s0 = *reinterpret_cast<const float4*>(&acc_lds[0][el]);
    const float4 s1 = *reinterpret_cast<const float4*>(&acc_lds[1][el]);
    const float4 s2 = *reinterpret_cast<const float4*>(&acc_lds[2][el]);
    const float4 s3 = *reinterpret_cast<const float4*>(&acc_lds[3][el]);
    const float r0v = s0.x + s1.x + s2.x + s3.x;
    const float r1v = s0.y + s1.y + s2.y + s3.y;
    const float r2v = s0.z + s1.z + s2.z + s3.z;
    const float r3v = s0.w + s1.w + s2.w + s3.w;
    float* op = out + ((size_t)(b << 10) + el) * H_ + h;   // out[b][d*32+e][h]
    op[0*H_] = r0v; op[1*H_] = r1v; op[2*H_] = r2v; op[3*H_] = r3v;
  }
}

extern "C" void kernel_launch(void* const* d_in, const int* in_sizes, int n_in,
                              void* d_out, int out_size, void* d_ws, size_t ws_size,
                              hipStream_t stream) {
  const float* token = (const float*)d_in[0];
  const float* Wkv   = (const float*)d_in[1];
  const float* Wkvh  = (const float*)d_in[2];
  const float* Wdec  = (const float*)d_in[3];
  const float* Wdech = (const float*)d_in[4];
  float* ws  = (float*)d_ws;   // needs ~14.2 MB
  float* out = (float*)d_out;

  proj_gemm<<<dim3(64, 14), 256, 0, stream>>>(token, Wkv, Wkvh, Wdec, Wdech, ws);
  scan_outer<<<B_ * H_, 256, 0, stream>>>(ws, out);
}

// Round 2
// 143.659 us; speedup vs baseline: 1.4739x; 1.4739x over previous
//
#include <hip/hip_runtime.h>

#define B_ 4
#define N_ 1024
#define H_ 256

// ---------- ws layout (bytes) ----------
// W_hi bf16 [896][256]      @ 0         (458752)
// W_lo bf16 [896][256]      @ 458752    (458752)
// kvb  f32  [4][1024][64]   @ 917504    (1048576)
// dd   f32  [4][1024][32]   @ 1966080   (524288)
// kh   bf16 [4][256][1024]  @ 2490368   (2097152)
// vh   bf16 [4][256][1024]  @ 4587520   (2097152)
// dh   f32  [4][256][1024]  @ 6684672   (4194304)  end = 10878976 < 14155776 (proven ws)
// tok_hi/tok_lo bf16 (2MB+2MB) live in d_out (exactly 4MB), overwritten by scan at the end.

typedef __attribute__((ext_vector_type(8))) short bf16x8;
typedef __attribute__((ext_vector_type(4))) float f32x4;

__device__ __forceinline__ short f2bf(float x) {
  union { float f; unsigned u; } c; c.f = x;
  unsigned r = (c.u + 0x7FFFu + ((c.u >> 16) & 1u)) >> 16;
  return (short)r;
}
__device__ __forceinline__ float bf2f(short s) {
  union { unsigned u; float f; } c; c.u = ((unsigned)(unsigned short)s) << 16;
  return c.f;
}
__device__ __forceinline__ float rcp_fast(float x) {
#if __has_builtin(__builtin_amdgcn_rcpf)
  return __builtin_amdgcn_rcpf(x);
#else
  return 1.0f / x;
#endif
}
__device__ __forceinline__ float sigm(float x) { return rcp_fast(1.0f + __expf(-x)); }

// ---------------- Kernel 1: f32 -> bf16 hi/lo conversion ----------------
// blocks 0..1023: token (1M elems, 4/thread). blocks 1024..1919: weights -> Bt[c][k] hi/lo.
__global__ __launch_bounds__(256) void convert_all(
    const float* __restrict__ token,
    const float* __restrict__ Wkv, const float* __restrict__ Wkvh,
    const float* __restrict__ Wdec, const float* __restrict__ Wdech,
    short* __restrict__ tok_hi, short* __restrict__ tok_lo,
    short* __restrict__ w_hi, short* __restrict__ w_lo)
{
  const int bid = blockIdx.x, tid = threadIdx.x;
  if (bid < 1024) {
    const int idx = bid * 256 + tid;                 // float4 index, 262144 total
    const float4 x = reinterpret_cast<const float4*>(token)[idx];
    short4 h, l;
    h.x = f2bf(x.x); l.x = f2bf(x.x - bf2f(h.x));
    h.y = f2bf(x.y); l.y = f2bf(x.y - bf2f(h.y));
    h.z = f2bf(x.z); l.z = f2bf(x.z - bf2f(h.z));
    h.w = f2bf(x.w); l.w = f2bf(x.w - bf2f(h.w));
    reinterpret_cast<short4*>(tok_hi)[idx] = h;
    reinterpret_cast<short4*>(tok_lo)[idx] = l;
  } else {
    const int c = bid - 1024;                        // output column 0..895
    const int k = tid;                               // K index 0..255
    float s = 0.0f;
    if (c < 64)       s = Wkv[k * 64 + c];
    else if (c < 576) s = Wkvh[k * 512 + (c - 64)];
    else if (c < 608) s = Wdec[k * 32 + (c - 576)];
    else if (c < 864) s = Wdech[k * 256 + (c - 608)];
    const short h = f2bf(s);
    const short l = f2bf(s - bf2f(h));
    w_hi[c * 256 + k] = h;
    w_lo[c * 256 + k] = l;
  }
}

// ---------------- Kernel 2: MFMA projection GEMM ----------------
// C(4096x896) = [t_hi | t_lo | t_hi](4096x768) @ [W_hi ; W_hi ; W_lo](768x896)
// (hi*Hi + lo*Hi + hi*Lo; dropped lo*Lo ~ 2^-18). One wave per 64x64 tile,
// direct global->VGPR fragments (all operands L2-resident), 16 MFMA / K-step.
__global__ __launch_bounds__(64) void mfma_proj(
    const short* __restrict__ tok_hi, const short* __restrict__ tok_lo,
    const short* __restrict__ w_hi, const short* __restrict__ w_lo,
    float* __restrict__ kvb, float* __restrict__ dd,
    short* __restrict__ kh, short* __restrict__ vh, float* __restrict__ dh)
{
  const int lane = threadIdx.x;
  const int r0 = blockIdx.x * 64;     // token row tile
  const int c0 = blockIdx.y * 64;     // output col tile
  const int row16 = lane & 15;        // A: m row / B: n col
  const int kgrp = lane >> 4;         // k-subgroup (8 contiguous k each)

  f32x4 acc[4][4];
#pragma unroll
  for (int mi = 0; mi < 4; ++mi)
#pragma unroll
    for (int ni = 0; ni < 4; ++ni)
#pragma unroll
      for (int r = 0; r < 4; ++r) acc[mi][ni][r] = 0.0f;

#pragma unroll 1
  for (int seg = 0; seg < 3; ++seg) {
    const short* Ap = (seg == 1) ? tok_lo : tok_hi;
    const short* Bp = (seg == 2) ? w_lo : w_hi;
#pragma unroll 1
    for (int k0 = 0; k0 < 256; k0 += 32) {
      bf16x8 a[4], b[4];
#pragma unroll
      for (int mi = 0; mi < 4; ++mi)
        a[mi] = *reinterpret_cast<const bf16x8*>(
            Ap + (size_t)(r0 + mi * 16 + row16) * 256 + k0 + kgrp * 8);
#pragma unroll
      for (int ni = 0; ni < 4; ++ni)
        b[ni] = *reinterpret_cast<const bf16x8*>(
            Bp + (size_t)(c0 + ni * 16 + row16) * 256 + k0 + kgrp * 8);
#pragma unroll
      for (int mi = 0; mi < 4; ++mi)
#pragma unroll
        for (int ni = 0; ni < 4; ++ni)
          acc[mi][ni] = __builtin_amdgcn_mfma_f32_16x16x32_bf16(a[mi], b[ni], acc[mi][ni], 0, 0, 0);
    }
  }

  // Epilogue. C/D frag: col = lane&15, row = (lane>>4)*4 + reg  (4 consecutive n, fixed col).
  const int b = r0 >> 10;             // block-uniform (64 | 1024)
#pragma unroll
  for (int mi = 0; mi < 4; ++mi) {
    const int n = ((r0 + mi * 16 + (lane >> 4) * 4) & (N_ - 1));
#pragma unroll
    for (int ni = 0; ni < 4; ++ni) {
      const int cb = c0 + ni * 16;                  // region-uniform (boundaries are x16)
      const int col = cb + (lane & 15);
      const f32x4 v = acc[mi][ni];
      if (cb < 64) {                                 // kv -> [b][n][64] f32
#pragma unroll
        for (int r = 0; r < 4; ++r)
          kvb[((size_t)(b << 10) + n + r) * 64 + col] = v[r];
      } else if (cb < 320) {                         // k_h -> [b][h][n] bf16
        short4 s; s.x = f2bf(v[0]); s.y = f2bf(v[1]); s.z = f2bf(v[2]); s.w = f2bf(v[3]);
        *reinterpret_cast<short4*>(kh + (((size_t)(b * H_ + (col - 64))) << 10) + n) = s;
      } else if (cb < 576) {                         // v_h -> [b][h][n] bf16
        short4 s; s.x = f2bf(v[0]); s.y = f2bf(v[1]); s.z = f2bf(v[2]); s.w = f2bf(v[3]);
        *reinterpret_cast<short4*>(vh + (((size_t)(b * H_ + (col - 320))) << 10) + n) = s;
      } else if (cb < 608) {                         // decay_d -> [b][n][32] f32
#pragma unroll
        for (int r = 0; r < 4; ++r)
          dd[((size_t)(b << 10) + n + r) * 32 + (col - 576)] = v[r];
      } else if (cb < 864) {                         // decay_h -> [b][h][n] f32
        *reinterpret_cast<float4*>(dh + (((size_t)(b * H_ + (col - 608))) << 10) + n) =
            make_float4(v[0], v[1], v[2], v[3]);
      }                                              // cb >= 864: padding, skip
    }
  }
}

// ---------------- Kernel 3: decay scan + 32x32 outer product ----------------
// One block per (b,h). 16 chunks of 64 rows; wave w owns chunks w, w+4, w+8, w+12.
// weight[i] = prod_{u=1..i} sigmoid(decay[N-u])  -> underflows to EXACT 0 fast;
// __all(run==0) chunk-skip is bit-exact vs the f32 semantics.
__global__ __launch_bounds__(256) void scan_outer(
    const float* __restrict__ kvb_all, const float* __restrict__ dd_all,
    const short* __restrict__ kh_all, const short* __restrict__ vh_all,
    const float* __restrict__ dh_all, float* __restrict__ out)
{
  const int bh = blockIdx.x;
  const int b = bh >> 8, h = bh & (H_ - 1);
  const int tid = threadIdx.x;
  const int w = tid >> 6, lane = tid & 63, d = lane & 31;

  const float* kvb = kvb_all + (size_t)b * (N_ * 64);
  const float* dd  = dd_all + (size_t)b * (N_ * 32);
  const short* khp = kh_all + ((size_t)(b * H_ + h) << 10);
  const short* vhp = vh_all + ((size_t)(b * H_ + h) << 10);
  const float* dhp = dh_all + ((size_t)(b * H_ + h) << 10);

  __shared__ float q_lds[16 * 32];        // per-chunk sigmoid products Q[c][d]
  __shared__ float acc_lds[4][1024];

  // Phase 1: chunk products. Two rows per iter via half-waves.
  for (int c = w; c < 16; c += 4) {
    float p = 1.0f;
    for (int s = 0; s < 32; ++s) {
      const int i = c * 64 + 2 * s + (lane >> 5);
      if (i > 0) {
        const int mr = N_ - i;
        p *= sigm(dd[mr * 32 + d] * dhp[mr]);
      }
    }
    p *= __shfl_xor(p, 32, 64);
    if (lane < 32) q_lds[c * 32 + d] = p;
  }
  __syncthreads();

  // Phase 2: carry-seeded local scans with exact-zero early exit.
  float run = 1.0f;
  for (int c0 = 0; c0 < w; ++c0) run *= q_lds[c0 * 32 + d];

  float acc[4][4] = {{0.f,0.f,0.f,0.f},{0.f,0.f,0.f,0.f},{0.f,0.f,0.f,0.f},{0.f,0.f,0.f,0.f}};
  const int d4 = (lane & 7) * 4;          // 8x8 lane grid of 4x4 tiles
  const int e4 = (lane >> 3) * 4;
  const short* sp = (lane < 32) ? khp : vhp;

  for (int c = w; c < 16; c += 4) {
    if (__all(run == 0.0f)) break;        // exact: all future k contributions are 0
    for (int t = 0; t < 64; ++t) {
      const int i = c * 64 + t;
      const float val = kvb[i * 64 + lane];       // lanes<32: k-proj, >=32: v-proj
      const float sc = bf2f(sp[i]);
      const int mr = (i == 0) ? 1 : (N_ - i);     // clamped; factor unused at i==0
      const float dx = dd[mr * 32 + d] * dhp[mr];
      const float x = val * sc;
      const float sv = x * sigm(x);               // silu
      const float fs = sigm(dx);
      if (i > 0) run *= fs;                       // wave-uniform branch
      const float myv = (lane < 32) ? sv * run : sv;

      float a4v[4], b4v[4];
#pragma unroll
      for (int p2 = 0; p2 < 4; ++p2) a4v[p2] = __shfl(myv, d4 + p2, 64);
#pragma unroll
      for (int q2 = 0; q2 < 4; ++q2) b4v[q2] = __shfl(myv, 32 + e4 + q2, 64);
#pragma unroll
      for (int p2 = 0; p2 < 4; ++p2)
#pragma unroll
        for (int q2 = 0; q2 < 4; ++q2)
          acc[p2][q2] = fmaf(a4v[p2], b4v[q2], acc[p2][q2]);
    }
    for (int cc = c + 1; cc < c + 4 && cc < 16; ++cc) run *= q_lds[cc * 32 + d];
  }

  // Combine 4 wave partials, store out[b][d*32+e][h].
#pragma unroll
  for (int p2 = 0; p2 < 4; ++p2)
#pragma unroll
    for (int q2 = 0; q2 < 4; ++q2)
      acc_lds[w][(d4 + p2) * 32 + (e4 + q2)] = acc[p2][q2];
  __syncthreads();

  {
    const int el = tid * 4;
    const float4 s0 = *reinterpret_cast<const float4*>(&acc_lds[0][el]);
    const float4 s1 = *reinterpret_cast<const float4*>(&acc_lds[1][el]);
    const float4 s2 = *reinterpret_cast<const float4*>(&acc_lds[2][el]);
    const float4 s3 = *reinterpret_cast<const float4*>(&acc_lds[3][el]);
    float* op = out + ((size_t)(b << 10) + el) * H_ + h;
    op[0 * H_] = s0.x + s1.x + s2.x + s3.x;
    op[1 * H_] = s0.y + s1.y + s2.y + s3.y;
    op[2 * H_] = s0.z + s1.z + s2.z + s3.z;
    op[3 * H_] = s0.w + s1.w + s2.w + s3.w;
  }
}

extern "C" void kernel_launch(void* const* d_in, const int* in_sizes, int n_in,
                              void* d_out, int out_size, void* d_ws, size_t ws_size,
                              hipStream_t stream) {
  const float* token = (const float*)d_in[0];
  const float* Wkv   = (const float*)d_in[1];
  const float* Wkvh  = (const float*)d_in[2];
  const float* Wdec  = (const float*)d_in[3];
  const float* Wdech = (const float*)d_in[4];
  float* out = (float*)d_out;

  // tok hi/lo scratch lives in d_out (exactly 4MB); overwritten by scan_outer at the end.
  short* tok_hi = (short*)d_out;
  short* tok_lo = tok_hi + 1048576;

  char* wsb = (char*)d_ws;
  short* w_hi = (short*)(wsb + 0);
  short* w_lo = (short*)(wsb + 458752);
  float* kvb  = (float*)(wsb + 917504);
  float* dd   = (float*)(wsb + 1966080);
  short* kh   = (short*)(wsb + 2490368);
  short* vh   = (short*)(wsb + 4587520);
  float* dh   = (float*)(wsb + 6684672);

  convert_all<<<1920, 256, 0, stream>>>(token, Wkv, Wkvh, Wdec, Wdech,
                                        tok_hi, tok_lo, w_hi, w_lo);
  mfma_proj<<<dim3(64, 14), 64, 0, stream>>>(tok_hi, tok_lo, w_hi, w_lo,
                                             kvb, dd, kh, vh, dh);
  scan_outer<<<B_ * H_, 256, 0, stream>>>(kvb, dd, kh, vh, dh, out);
}

// Round 3
// 123.004 us; speedup vs baseline: 1.7214x; 1.1679x over previous
//
#include <hip/hip_runtime.h>

#define B_ 4
#define N_ 1024
#define H_ 256

// ---------- ws layout (bytes), total 14155776 (== proven R2 size) ----------
// wout f32 [4][256][1024] @ 0        (4194304)   scan output, [b][h][de]
//   w_hi bf16 [896][256]  @ 0        (458752)    dead after proj (overlaid)
//   w_lo bf16 [896][256]  @ 458752   (458752)    dead after proj (overlaid)
// kvb  f32  [4][1024][64] @ 4194304  (1048576)
// dd   f32  [4][1024][32] @ 5242880  (524288)
// kh   bf16 [4][256][1024]@ 5767168  (2097152)
// vh   bf16 [4][256][1024]@ 7864320  (2097152)
// dh   f32  [4][256][1024]@ 9961472  (4194304)
// tok_hi/tok_lo bf16 (2MB+2MB) live in d_out; dead after mfma_proj.

typedef __attribute__((ext_vector_type(8))) short bf16x8;
typedef __attribute__((ext_vector_type(4))) float f32x4;
typedef __attribute__((ext_vector_type(16))) float f32x16;

__device__ __forceinline__ short f2bf(float x) {
  union { float f; unsigned u; } c; c.f = x;
  unsigned r = (c.u + 0x7FFFu + ((c.u >> 16) & 1u)) >> 16;
  return (short)r;
}
__device__ __forceinline__ float bf2f(short s) {
  union { unsigned u; float f; } c; c.u = ((unsigned)(unsigned short)s) << 16;
  return c.f;
}
__device__ __forceinline__ float rcp_fast(float x) {
#if __has_builtin(__builtin_amdgcn_rcpf)
  return __builtin_amdgcn_rcpf(x);
#else
  return 1.0f / x;
#endif
}
__device__ __forceinline__ float sigm(float x) { return rcp_fast(1.0f + __expf(-x)); }
__device__ __forceinline__ unsigned cvt_pk_bf16(float lo, float hi) {
  unsigned r;
  asm("v_cvt_pk_bf16_f32 %0, %1, %2" : "=v"(r) : "v"(lo), "v"(hi));
  return r;
}

// ---------------- Kernel 1: f32 -> bf16 hi/lo conversion ----------------
__global__ __launch_bounds__(256) void convert_all(
    const float* __restrict__ token,
    const float* __restrict__ Wkv, const float* __restrict__ Wkvh,
    const float* __restrict__ Wdec, const float* __restrict__ Wdech,
    short* __restrict__ tok_hi, short* __restrict__ tok_lo,
    short* __restrict__ w_hi, short* __restrict__ w_lo)
{
  const int bid = blockIdx.x, tid = threadIdx.x;
  if (bid < 1024) {
    const int idx = bid * 256 + tid;                 // float4 index, 262144 total
    const float4 x = reinterpret_cast<const float4*>(token)[idx];
    short4 h, l;
    h.x = f2bf(x.x); l.x = f2bf(x.x - bf2f(h.x));
    h.y = f2bf(x.y); l.y = f2bf(x.y - bf2f(h.y));
    h.z = f2bf(x.z); l.z = f2bf(x.z - bf2f(h.z));
    h.w = f2bf(x.w); l.w = f2bf(x.w - bf2f(h.w));
    reinterpret_cast<short4*>(tok_hi)[idx] = h;
    reinterpret_cast<short4*>(tok_lo)[idx] = l;
  } else {
    const int c = bid - 1024;                        // output column 0..895
    const int k = tid;
    float s = 0.0f;
    if (c < 64)       s = Wkv[k * 64 + c];
    else if (c < 576) s = Wkvh[k * 512 + (c - 64)];
    else if (c < 608) s = Wdec[k * 32 + (c - 576)];
    else if (c < 864) s = Wdech[k * 256 + (c - 608)];
    const short h = f2bf(s);
    const short l = f2bf(s - bf2f(h));
    w_hi[c * 256 + k] = h;
    w_lo[c * 256 + k] = l;
  }
}

// ---------------- Kernel 2: MFMA projection GEMM (128x128 tile, 4 waves) ----------------
// C(4096x896) = [t_hi | t_lo | t_hi](4096x768) @ [W_hi ; W_hi ; W_lo](768x896)
__global__ __launch_bounds__(256) void mfma_proj(
    const short* __restrict__ tok_hi, const short* __restrict__ tok_lo,
    const short* __restrict__ w_hi, const short* __restrict__ w_lo,
    float* __restrict__ kvb, float* __restrict__ dd,
    short* __restrict__ kh, short* __restrict__ vh, float* __restrict__ dh)
{
  __shared__ __align__(16) char As_lds[16384];   // [128 rows][64 k] bf16, XOR-swizzled
  __shared__ __align__(16) char Bs_lds[16384];   // [128 cols][64 k]
  const int tid = threadIdx.x;
  const int lane = tid & 63;
  const int wid = tid >> 6;
  const int wrow = (wid >> 1) * 64;
  const int wcol = (wid & 1) * 64;
  const int R0b = blockIdx.x * 128;
  const int C0b = blockIdx.y * 128;

  f32x4 acc[4][4];
#pragma unroll
  for (int mi = 0; mi < 4; ++mi)
#pragma unroll
    for (int ni = 0; ni < 4; ++ni)
#pragma unroll
      for (int r = 0; r < 4; ++r) acc[mi][ni][r] = 0.0f;

#pragma unroll 1
  for (int step = 0; step < 12; ++step) {
    const int seg = step >> 2;
    const int k0b = (step & 3) * 128;              // byte offset within 512B row
    const short* Asrc = (seg == 1) ? tok_lo : tok_hi;
    const short* Bsrc = (seg == 2) ? w_lo : w_hi;
    __syncthreads();                               // previous compute done
#pragma unroll
    for (int i = 0; i < 4; ++i) {
      const int row = i * 32 + (tid >> 3);
      const int wb = (tid & 7) * 16;
      const int sw = wb ^ ((row & 7) << 4);        // T2 swizzle on write
      const float4 va = *reinterpret_cast<const float4*>(
          (const char*)Asrc + (size_t)(R0b + row) * 512 + k0b + wb);
      *reinterpret_cast<float4*>(&As_lds[row * 128 + sw]) = va;
      const float4 vb = *reinterpret_cast<const float4*>(
          (const char*)Bsrc + (size_t)(C0b + row) * 512 + k0b + wb);
      *reinterpret_cast<float4*>(&Bs_lds[row * 128 + sw]) = vb;
    }
    __syncthreads();
#pragma unroll
    for (int ks = 0; ks < 2; ++ks) {
      bf16x8 a[4], b[4];
      const int wb = ks * 64 + (lane >> 4) * 16;
#pragma unroll
      for (int mi = 0; mi < 4; ++mi) {
        const int row = wrow + mi * 16 + (lane & 15);
        a[mi] = *reinterpret_cast<const bf16x8*>(&As_lds[row * 128 + (wb ^ ((row & 7) << 4))]);
      }
#pragma unroll
      for (int ni = 0; ni < 4; ++ni) {
        const int col = wcol + ni * 16 + (lane & 15);
        b[ni] = *reinterpret_cast<const bf16x8*>(&Bs_lds[col * 128 + (wb ^ ((col & 7) << 4))]);
      }
#pragma unroll
      for (int mi = 0; mi < 4; ++mi)
#pragma unroll
        for (int ni = 0; ni < 4; ++ni)
          acc[mi][ni] = __builtin_amdgcn_mfma_f32_16x16x32_bf16(a[mi], b[ni], acc[mi][ni], 0, 0, 0);
    }
  }

  // Epilogue. C/D frag: col = lane&15, row = (lane>>4)*4 + reg.
  const int R0 = R0b + wrow, c0 = C0b + wcol;
  const int b = R0 >> 10;
#pragma unroll
  for (int mi = 0; mi < 4; ++mi) {
    const int n = ((R0 + mi * 16 + (lane >> 4) * 4) & (N_ - 1));
#pragma unroll
    for (int ni = 0; ni < 4; ++ni) {
      const int cb = c0 + ni * 16;
      const int col = cb + (lane & 15);
      const f32x4 v = acc[mi][ni];
      if (cb < 64) {                                 // kv -> [b][n][64] f32
#pragma unroll
        for (int r = 0; r < 4; ++r)
          kvb[((size_t)(b << 10) + n + r) * 64 + col] = v[r];
      } else if (cb < 320) {                         // k_h -> [b][h][n] bf16
        short4 s; s.x = f2bf(v[0]); s.y = f2bf(v[1]); s.z = f2bf(v[2]); s.w = f2bf(v[3]);
        *reinterpret_cast<short4*>(kh + (((size_t)(b * H_ + (col - 64))) << 10) + n) = s;
      } else if (cb < 576) {                         // v_h -> [b][h][n] bf16
        short4 s; s.x = f2bf(v[0]); s.y = f2bf(v[1]); s.z = f2bf(v[2]); s.w = f2bf(v[3]);
        *reinterpret_cast<short4*>(vh + (((size_t)(b * H_ + (col - 320))) << 10) + n) = s;
      } else if (cb < 608) {                         // decay_d -> [b][n][32] f32
#pragma unroll
        for (int r = 0; r < 4; ++r)
          dd[((size_t)(b << 10) + n + r) * 32 + (col - 576)] = v[r];
      } else if (cb < 864) {                         // decay_h -> [b][h][n] f32
        *reinterpret_cast<float4*>(dh + (((size_t)(b * H_ + (col - 608))) << 10) + n) =
            make_float4(v[0], v[1], v[2], v[3]);
      }
    }
  }
}

// ---------------- Kernel 3: decay scan + MFMA outer product ----------------
// One block per (b,h). 4 waves; 16 chunks of 64 rows, round-robin by round.
// weight[i] = prod_{u=1..i} sigmoid(decay[N-u]); underflows to exact 0 -> block-uniform break.
__global__ __launch_bounds__(256) void scan_outer(
    const float* __restrict__ kvb_all, const float* __restrict__ dd_all,
    const short* __restrict__ kh_all, const short* __restrict__ vh_all,
    const float* __restrict__ dh_all, float* __restrict__ wout)
{
  const int bh = blockIdx.x;
  const int b = bh >> 8, h = bh & (H_ - 1);
  const int tid = threadIdx.x;
  const int w = tid >> 6, lane = tid & 63;
  const int d = lane & 31, grp = lane >> 5;

  const float* kvb = kvb_all + (size_t)b * (N_ * 64);
  const float* dd  = dd_all + (size_t)b * (N_ * 32);
  const short* khp = kh_all + ((size_t)(b * H_ + h) << 10);
  const short* vhp = vh_all + ((size_t)(b * H_ + h) << 10);
  const float* dhp = dh_all + ((size_t)(b * H_ + h) << 10);

  __shared__ float q_lds[15 * 32];      // chunk sigmoid-products Q[c][d], c=0..14
  __shared__ int dead_s[8];             // double-buffered per-round votes
  __shared__ float acc_lds[4][1024];

  // Phase 1: Q[c][d] for c=0..14 (2 rows/iter via half-waves)
  for (int c = w; c < 15; c += 4) {
    float p = 1.0f;
#pragma unroll 4
    for (int s = 0; s < 32; ++s) {
      const int i = c * 64 + 2 * s + grp;
      if (i > 0) p *= sigm(dd[(N_ - i) * 32 + d] * dhp[N_ - i]);
    }
    p *= __shfl_xor(p, 32, 64);
    if (lane < 32) q_lds[c * 32 + d] = p;
  }
  __syncthreads();

  f32x16 acc;
#pragma unroll
  for (int r = 0; r < 16; ++r) acc[r] = 0.0f;

  float C = 1.0f;                        // carry = prod Q[0..chunk-1] for my chunk
  for (int j = 0; j < w; ++j) C *= q_lds[j * 32 + d];

#pragma unroll 1
  for (int r = 0; r < 4; ++r) {
    const int c = 4 * r + w;
    const int par = (r & 1) * 4;
    const bool my_dead = __all(C == 0.0f);
    if (lane == 0) dead_s[par + w] = my_dead ? 1 : 0;
    __syncthreads();
    if (dead_s[par] && dead_s[par + 1] && dead_s[par + 2] && dead_s[par + 3]) break;
    if (!my_dead) {
      float Cc = C;
#pragma unroll 1
      for (int t = 0; t < 4; ++t) {
        const int base = c * 64 + t * 16 + grp * 8;   // my 8 rows: base..base+7
        float xk[8], xv[8], dx[8];
#pragma unroll
        for (int j = 0; j < 8; ++j) {
          const int n = base + j;
          xk[j] = kvb[n * 64 + d] * bf2f(khp[n]);
          xv[j] = kvb[n * 64 + 32 + d] * bf2f(vhp[n]);
          const int mr = (n == 0) ? 1 : (N_ - n);
          dx[j] = dd[mr * 32 + d] * dhp[mr];
        }
        float p[8];
        p[0] = (base == 0) ? 1.0f : sigm(dx[0]);      // inclusive prefix of g
#pragma unroll
        for (int j = 1; j < 8; ++j) p[j] = p[j - 1] * sigm(dx[j]);
        const float tot = p[7];
        const float oth = __shfl_xor(tot, 32, 64);
        const float pre = Cc * (grp ? oth : 1.0f);
        union { unsigned u[4]; bf16x8 v; } A, Bv;
#pragma unroll
        for (int jj = 0; jj < 4; ++jj) {
          const int j0 = 2 * jj, j1 = 2 * jj + 1;
          const float a0 = xk[j0] * sigm(xk[j0]) * (pre * p[j0]);
          const float a1 = xk[j1] * sigm(xk[j1]) * (pre * p[j1]);
          const float b0 = xv[j0] * sigm(xv[j0]);
          const float b1 = xv[j1] * sigm(xv[j1]);
          A.u[jj] = cvt_pk_bf16(a0, a1);
          Bv.u[jj] = cvt_pk_bf16(b0, b1);
        }
        Cc *= tot * oth;
        acc = __builtin_amdgcn_mfma_f32_32x32x16_bf16(A.v, Bv.v, acc, 0, 0, 0);
      }
    }
    if (r < 3) {
#pragma unroll
      for (int j = 0; j < 4; ++j) C *= q_lds[(c + j) * 32 + d];   // max idx 14
    }
  }

  // Combine 4 wave partials. 32x32 C/D: col=lane&31, row=(reg&3)+8*(reg>>2)+4*grp.
#pragma unroll
  for (int rg = 0; rg < 16; ++rg) {
    const int m = (rg & 3) + 8 * (rg >> 2) + 4 * grp;
    acc_lds[w][m * 32 + d] = acc[rg];
  }
  __syncthreads();
  {
    const int el = tid * 4;
    const float4 s0 = *reinterpret_cast<const float4*>(&acc_lds[0][el]);
    const float4 s1 = *reinterpret_cast<const float4*>(&acc_lds[1][el]);
    const float4 s2 = *reinterpret_cast<const float4*>(&acc_lds[2][el]);
    const float4 s3 = *reinterpret_cast<const float4*>(&acc_lds[3][el]);
    // coalesced store: wout[b][h][de]
    float4 st;
    st.x = s0.x + s1.x + s2.x + s3.x;
    st.y = s0.y + s1.y + s2.y + s3.y;
    st.z = s0.z + s1.z + s2.z + s3.z;
    st.w = s0.w + s1.w + s2.w + s3.w;
    *reinterpret_cast<float4*>(&wout[(((size_t)(b * H_ + h)) << 10) + el]) = st;
  }
}

// ---------------- Kernel 4: transpose [b][h][de] -> out[b][de][h] ----------------
__global__ __launch_bounds__(256) void out_transpose(const float* __restrict__ wout,
                                                     float* __restrict__ out)
{
  __shared__ float T[64][65];
  const int bid = blockIdx.x;            // 256 blocks: b(4) x de_t(16) x h_t(4)
  const int b = bid >> 6, de_t = (bid >> 2) & 15, h_t = bid & 3;
  const int de0 = de_t * 64, h0 = h_t * 64;
  const int tid = threadIdx.x;
  const float* src = wout + (size_t)b * (H_ * N_);
  float* dst = out + (size_t)b * (N_ * H_);

#pragma unroll
  for (int q = 0; q < 4; ++q) {
    const int idx = q * 256 + tid;
    const int rh = idx >> 4, c4 = idx & 15;
    const float4 v = *reinterpret_cast<const float4*>(&src[(h0 + rh) * N_ + de0 + c4 * 4]);
    T[c4 * 4 + 0][rh] = v.x; T[c4 * 4 + 1][rh] = v.y;
    T[c4 * 4 + 2][rh] = v.z; T[c4 * 4 + 3][rh] = v.w;
  }
  __syncthreads();
#pragma unroll
  for (int q = 0; q < 4; ++q) {
    const int idx = q * 256 + tid;
    const int rd = idx >> 4, c4 = idx & 15;
    float4 v;
    v.x = T[rd][c4 * 4 + 0]; v.y = T[rd][c4 * 4 + 1];
    v.z = T[rd][c4 * 4 + 2]; v.w = T[rd][c4 * 4 + 3];
    *reinterpret_cast<float4*>(&dst[(de0 + rd) * H_ + h0 + c4 * 4]) = v;
  }
}

extern "C" void kernel_launch(void* const* d_in, const int* in_sizes, int n_in,
                              void* d_out, int out_size, void* d_ws, size_t ws_size,
                              hipStream_t stream) {
  const float* token = (const float*)d_in[0];
  const float* Wkv   = (const float*)d_in[1];
  const float* Wkvh  = (const float*)d_in[2];
  const float* Wdec  = (const float*)d_in[3];
  const float* Wdech = (const float*)d_in[4];
  float* out = (float*)d_out;

  // tok hi/lo scratch in d_out (4MB exactly); dead after mfma_proj.
  short* tok_hi = (short*)d_out;
  short* tok_lo = tok_hi + 1048576;

  char* wsb = (char*)d_ws;
  float* wout = (float*)(wsb + 0);         // 4MB; overlays w_hi/w_lo
  short* w_hi = (short*)(wsb + 0);
  short* w_lo = (short*)(wsb + 458752);
  float* kvb  = (float*)(wsb + 4194304);
  float* dd   = (float*)(wsb + 5242880);
  short* kh   = (short*)(wsb + 5767168);
  short* vh   = (short*)(wsb + 7864320);
  float* dh   = (float*)(wsb + 9961472);

  convert_all<<<1920, 256, 0, stream>>>(token, Wkv, Wkvh, Wdec, Wdech,
                                        tok_hi, tok_lo, w_hi, w_lo);
  mfma_proj<<<dim3(32, 7), 256, 0, stream>>>(tok_hi, tok_lo, w_hi, w_lo,
                                             kvb, dd, kh, vh, dh);
  scan_outer<<<B_ * H_, 256, 0, stream>>>(kvb, dd, kh, vh, dh, wout);
  out_transpose<<<256, 256, 0, stream>>>(wout, out);
}